// Round 5
// baseline (1650.628 us; speedup 1.0000x reference)
//
#include <hip/hip_runtime.h>

// ElmanRNN: out[b][s][h] = tanh(x[b][s]@W_ih^T + b_ih + b_hh + h_prev@W_hh^T)
// B=64 S=1024 I=H=512, fp32 in/out.
//
// Kernel 1: x_proj GEMM (bf16 MFMA, 128x128 tile) written IN-PLACE into d_out.
// Kernel 2: recurrence, 64 WGs (1/batch), 512 threads own one h-row each.
//   W_hh row cols 0..383 intended in 192 f16x2 VGPRs. Rounds 2-4 all came back
//   VGPR_Count=128 / 1.54us/step == per-CU L2-read roofline: the allocator
//   REMATERIALIZES the loop-invariant W loads from L2 every step (no scratch
//   traffic in FETCH_SIZE -> not spilling; L1<-L2 traffic is invisible to TCC
//   counters). Cause: dynamic LDS size is unknown at compile time, so the
//   occupancy heuristic targets 4 waves/SIMD = 128 VGPRs. Fix: pin the budget
//   with amdgpu_waves_per_eu(2,2) -> exactly 256 VGPRs/wave.
//   Cols 384..511 in LDS (128KB). h double-buffered in LDS, broadcast reads.

typedef _Float16 f16;
typedef _Float16 f16x2 __attribute__((ext_vector_type(2)));
typedef _Float16 f16x8 __attribute__((ext_vector_type(8)));
typedef short    s16x8 __attribute__((ext_vector_type(8)));
typedef float    f32x4 __attribute__((ext_vector_type(4)));

#define NB 64
#define NS 1024
#define NI 512
#define NH 512

__device__ __forceinline__ short f2bf(float f) {
  unsigned u = __builtin_bit_cast(unsigned, f);
  u = (u + 0x7FFFu + ((u >> 16) & 1u)) >> 16;   // RNE
  return (short)u;
}

#if __has_builtin(__builtin_amdgcn_fdot2)
__device__ __forceinline__ float dot2(f16x2 a, f16x2 b, float c) {
  return __builtin_amdgcn_fdot2(a, b, c, false);
}
#else
__device__ __forceinline__ float dot2(f16x2 a, f16x2 b, float c) {
  return c + (float)a.x * (float)b.x + (float)a.y * (float)b.y;
}
#endif

__device__ __forceinline__ float tanh_fast(float x) {
#if __has_builtin(__builtin_amdgcn_exp2f)
  float e = __builtin_amdgcn_exp2f(x * 2.8853900817779268f);  // 2*log2(e)
#else
  float e = exp2f(x * 2.8853900817779268f);
#endif
#if __has_builtin(__builtin_amdgcn_rcpf)
  return 1.f - 2.f * __builtin_amdgcn_rcpf(e + 1.f);
#else
  return 1.f - 2.f / (e + 1.f);
#endif
}

// ---------------- Kernel 1: x_proj = x @ W_ih^T + (b_ih + b_hh) ----------------
#define BM 128
#define BN 128
#define BK 32
#define KP 40   // padded row stride in bf16 elems

__global__ __launch_bounds__(256) void xproj_gemm(
    const float* __restrict__ X, const float* __restrict__ W,
    const float* __restrict__ bih, const float* __restrict__ bhh,
    float* __restrict__ out)
{
  __shared__ short As[BM * KP];
  __shared__ short Bs[BN * KP];
  const int t  = threadIdx.x;
  const int mt = blockIdx.x >> 2;
  const int nt = blockIdx.x & 3;
  const int m0 = mt * BM, n0 = nt * BN;
  const int lane = t & 63, wv = t >> 6;
  const int wm = (wv & 1) * 64, wn = (wv >> 1) * 64;
  const int l15 = lane & 15, l4 = lane >> 4;

  const int sr = t >> 1;
  const int sk = (t & 1) * 16;
  const float* xa = X + (size_t)(m0 + sr) * NI + sk;
  const float* wa = W + (size_t)(n0 + sr) * NI + sk;
  short* asw = &As[sr * KP + sk];
  short* bsw = &Bs[sr * KP + sk];

  f32x4 acc[4][4];
  #pragma unroll
  for (int i = 0; i < 4; ++i)
    #pragma unroll
    for (int j = 0; j < 4; ++j)
      acc[i][j] = (f32x4){0.f, 0.f, 0.f, 0.f};

  for (int kt = 0; kt < NI; kt += BK) {
    float4 a0 = *(const float4*)(xa + kt);
    float4 a1 = *(const float4*)(xa + kt + 4);
    float4 a2 = *(const float4*)(xa + kt + 8);
    float4 a3 = *(const float4*)(xa + kt + 12);
    float4 b0 = *(const float4*)(wa + kt);
    float4 b1 = *(const float4*)(wa + kt + 4);
    float4 b2 = *(const float4*)(wa + kt + 8);
    float4 b3 = *(const float4*)(wa + kt + 12);
    s16x8 av0 = { f2bf(a0.x), f2bf(a0.y), f2bf(a0.z), f2bf(a0.w),
                  f2bf(a1.x), f2bf(a1.y), f2bf(a1.z), f2bf(a1.w) };
    s16x8 av1 = { f2bf(a2.x), f2bf(a2.y), f2bf(a2.z), f2bf(a2.w),
                  f2bf(a3.x), f2bf(a3.y), f2bf(a3.z), f2bf(a3.w) };
    s16x8 bv0 = { f2bf(b0.x), f2bf(b0.y), f2bf(b0.z), f2bf(b0.w),
                  f2bf(b1.x), f2bf(b1.y), f2bf(b1.z), f2bf(b1.w) };
    s16x8 bv1 = { f2bf(b2.x), f2bf(b2.y), f2bf(b2.z), f2bf(b2.w),
                  f2bf(b3.x), f2bf(b3.y), f2bf(b3.z), f2bf(b3.w) };

    __syncthreads();
    *(s16x8*)asw       = av0;
    *(s16x8*)(asw + 8) = av1;
    *(s16x8*)bsw       = bv0;
    *(s16x8*)(bsw + 8) = bv1;
    __syncthreads();

    s16x8 af[4], bf[4];
    #pragma unroll
    for (int mi = 0; mi < 4; ++mi)
      af[mi] = *(const s16x8*)&As[(wm + mi * 16 + l15) * KP + l4 * 8];
    #pragma unroll
    for (int ni = 0; ni < 4; ++ni)
      bf[ni] = *(const s16x8*)&Bs[(wn + ni * 16 + l15) * KP + l4 * 8];
    #pragma unroll
    for (int mi = 0; mi < 4; ++mi)
      #pragma unroll
      for (int ni = 0; ni < 4; ++ni)
        acc[mi][ni] = __builtin_amdgcn_mfma_f32_16x16x32_bf16(
            af[mi], bf[ni], acc[mi][ni], 0, 0, 0);
  }

  #pragma unroll
  for (int ni = 0; ni < 4; ++ni) {
    const int nloc = n0 + wn + ni * 16 + l15;
    const float bias = bih[nloc] + bhh[nloc];
    #pragma unroll
    for (int mi = 0; mi < 4; ++mi) {
      const int mrow = m0 + wm + mi * 16 + l4 * 4;
      #pragma unroll
      for (int j = 0; j < 4; ++j)
        out[(size_t)(mrow + j) * NH + nloc] = acc[mi][ni][j] + bias;
    }
  }
}

// ---------------- Kernel 2: per-batch recurrence, zero cross-WG sync ----------
// Thread t owns h-row t. Cols 0..383 of W_hh[t] in 192 NAMED f16x2 registers
// (48 groups x 4); cols 384..511 in LDS wq (16 f16x8 chunks = 128KB).
// h double-buffered in LDS as 256 f16x2, broadcast ds_read_b128.

#define KV 192                 // f16x2 pairs in VGPRs (cols < 384)
#define KQ 16                  // f16x8 chunks per row in LDS (cols [384,512))

#define FOR48(M) \
  M(0) M(1) M(2) M(3) M(4) M(5) M(6) M(7) M(8) M(9) \
  M(10) M(11) M(12) M(13) M(14) M(15) M(16) M(17) M(18) M(19) \
  M(20) M(21) M(22) M(23) M(24) M(25) M(26) M(27) M(28) M(29) \
  M(30) M(31) M(32) M(33) M(34) M(35) M(36) M(37) M(38) M(39) \
  M(40) M(41) M(42) M(43) M(44) M(45) M(46) M(47)

#define WDECL(g) f16x2 w##g##_0, w##g##_1, w##g##_2, w##g##_3;

#define WLOAD(g) { \
  float4 fa = row4[2 * (g)]; \
  float4 fb = row4[2 * (g) + 1]; \
  w##g##_0 = (f16x2){ (f16)fa.x, (f16)fa.y }; \
  w##g##_1 = (f16x2){ (f16)fa.z, (f16)fa.w }; \
  w##g##_2 = (f16x2){ (f16)fb.x, (f16)fb.y }; \
  w##g##_3 = (f16x2){ (f16)fb.z, (f16)fb.w }; }

#define WDOT(g) { \
  f16x8 hc = *(const f16x8*)&hb[4 * (g)]; \
  a0 = dot2(w##g##_0, (f16x2){ hc[0], hc[1] }, a0); \
  a1 = dot2(w##g##_1, (f16x2){ hc[2], hc[3] }, a1); \
  a2 = dot2(w##g##_2, (f16x2){ hc[4], hc[5] }, a2); \
  a3 = dot2(w##g##_3, (f16x2){ hc[6], hc[7] }, a3); }

__global__ __attribute__((amdgpu_flat_work_group_size(512, 512),
                          amdgpu_waves_per_eu(2, 2)))
void rnn_steps(const float* __restrict__ Whh, float* __restrict__ out)
{
  extern __shared__ f16x8 wq_raw[];                // [KQ][512]
  f16x8 (*wq)[512] = (f16x8(*)[512])wq_raw;
  __shared__ __align__(16) f16x2 hbuf[2][256];

  const int b = blockIdx.x;
  const int t = threadIdx.x;

  // ---- load W row t: cols 0..383 -> named VGPRs, 384..511 -> LDS ----
  const float4* row4 = (const float4*)(Whh + (size_t)t * NH);
  FOR48(WDECL)
  FOR48(WLOAD)
  #pragma unroll
  for (int q = 0; q < KQ; ++q) {                   // cols 384..511
    float4 fa = row4[KV / 2 + 2 * q];
    float4 fb = row4[KV / 2 + 2 * q + 1];
    wq[q][t] = (f16x8){ (f16)fa.x, (f16)fa.y, (f16)fa.z, (f16)fa.w,
                        (f16)fb.x, (f16)fb.y, (f16)fb.z, (f16)fb.w };
  }
  if (t < 256) {
    hbuf[0][t] = (f16x2){ (f16)0.f, (f16)0.f };
  }

  float* outp = out + (size_t)b * (NS * NH) + t;
  float xpv = outp[0];                       // xp for s=0 (xproj output)
  __syncthreads();

  for (int s = 0; s < NS; ++s) {
    // prefetch next step's xp early: latency hides under the dot product
    float xq = 0.f;
    if (s + 1 < NS) xq = outp[(size_t)(s + 1) * NH];

    const f16x2* hb = hbuf[s & 1];
    float a0 = 0.f, a1 = 0.f, a2 = 0.f, a3 = 0.f;
    FOR48(WDOT)                               // cols [0,384): W from VGPRs
    #pragma unroll
    for (int q = 0; q < KQ; ++q) {            // cols [384,512): W from LDS
      f16x8 wc = wq[q][t];                    // lane-consecutive 16B
      f16x8 hc = *(const f16x8*)&hb[KV + 4 * q];
      f16x2 w0 = { wc[0], wc[1] }, w1 = { wc[2], wc[3] };
      f16x2 w2 = { wc[4], wc[5] }, w3 = { wc[6], wc[7] };
      f16x2 h0 = { hc[0], hc[1] }, h1 = { hc[2], hc[3] };
      f16x2 h2 = { hc[4], hc[5] }, h3 = { hc[6], hc[7] };
      a0 = dot2(w0, h0, a0);
      a1 = dot2(w1, h1, a1);
      a2 = dot2(w2, h2, a2);
      a3 = dot2(w3, h3, a3);
    }
    const float y = (a0 + a1) + (a2 + a3);
    const float hval = tanh_fast(xpv + y);

    outp[(size_t)s * NH] = hval;              // coalesced 2KB store
    const float hnb = __shfl_xor(hval, 1);    // row-pair partner
    if ((t & 1) == 0)
      hbuf[(s + 1) & 1][t >> 1] = (f16x2){ (f16)hval, (f16)hnb };
    xpv = xq;
    __syncthreads();                          // next buffer ready
  }
}

// ---------------- launch ----------------
extern "C" void kernel_launch(void* const* d_in, const int* in_sizes, int n_in,
                              void* d_out, int out_size, void* d_ws, size_t ws_size,
                              hipStream_t stream) {
  const float* x   = (const float*)d_in[0];
  const float* Wih = (const float*)d_in[1];
  const float* Whh = (const float*)d_in[2];
  const float* bih = (const float*)d_in[3];
  const float* bhh = (const float*)d_in[4];
  float* out = (float*)d_out;

  xproj_gemm<<<dim3((NB * NS / BM) * (NH / BN)), dim3(256), 0, stream>>>(
      x, Wih, bih, bhh, out);

  const int dyn_lds = KQ * 512 * sizeof(f16x8);   // 128KB
  hipFuncSetAttribute((const void*)rnn_steps,
                      hipFuncAttributeMaxDynamicSharedMemorySize, dyn_lds);
  rnn_steps<<<dim3(NB), dim3(512), dyn_lds, stream>>>(Whh, out);
}

// Round 6
// 1622.352 us; speedup vs baseline: 1.0174x; 1.0174x over previous
//
#include <hip/hip_runtime.h>

// ElmanRNN: out[b][s][h] = tanh(x[b][s]@W_ih^T + b_ih + b_hh + h_prev@W_hh^T)
// B=64 S=1024 I=H=512, fp32 in/out.
//
// Kernel 1: x_proj GEMM (bf16 MFMA, 128x128 tile) written IN-PLACE into d_out.
// Kernel 2: recurrence, 64 WGs (1/batch), 512 threads own one h-row each.
//   W_hh row cols 0..383 in 192 f16x2 VGPRs. Rounds 2-5 all produced
//   VGPR_Count=128 / 1.54us/step == per-CU L2-read roofline: Whh is const
//   __restrict__, so the pressure-aware scheduler legally SINKS the W loads
//   into the step loop (re-read from L2 each step; invisible to FETCH_SIZE
//   because W is L2-resident). Occupancy attrs can't stop that. Fix: pin each
//   loaded W value with an empty inline-asm op (asm "+v") -> value is defined
//   by asm, non-rematerializable, def stays outside the loop, RA must keep it
//   in a VGPR (budget 256 via waves_per_eu(2,2)) or visibly spill to scratch.
//   Cols 384..511 in LDS (128KB). h double-buffered in LDS, broadcast reads.

typedef _Float16 f16;
typedef _Float16 f16x2 __attribute__((ext_vector_type(2)));
typedef _Float16 f16x8 __attribute__((ext_vector_type(8)));
typedef short    s16x8 __attribute__((ext_vector_type(8)));
typedef float    f32x4 __attribute__((ext_vector_type(4)));

#define NB 64
#define NS 1024
#define NI 512
#define NH 512

__device__ __forceinline__ short f2bf(float f) {
  unsigned u = __builtin_bit_cast(unsigned, f);
  u = (u + 0x7FFFu + ((u >> 16) & 1u)) >> 16;   // RNE
  return (short)u;
}

#if __has_builtin(__builtin_amdgcn_fdot2)
__device__ __forceinline__ float dot2(f16x2 a, f16x2 b, float c) {
  return __builtin_amdgcn_fdot2(a, b, c, false);
}
#else
__device__ __forceinline__ float dot2(f16x2 a, f16x2 b, float c) {
  return c + (float)a.x * (float)b.x + (float)a.y * (float)b.y;
}
#endif

__device__ __forceinline__ float tanh_fast(float x) {
#if __has_builtin(__builtin_amdgcn_exp2f)
  float e = __builtin_amdgcn_exp2f(x * 2.8853900817779268f);  // 2*log2(e)
#else
  float e = exp2f(x * 2.8853900817779268f);
#endif
#if __has_builtin(__builtin_amdgcn_rcpf)
  return 1.f - 2.f * __builtin_amdgcn_rcpf(e + 1.f);
#else
  return 1.f - 2.f / (e + 1.f);
#endif
}

// ---------------- Kernel 1: x_proj = x @ W_ih^T + (b_ih + b_hh) ----------------
#define BM 128
#define BN 128
#define BK 32
#define KP 40   // padded row stride in bf16 elems

__global__ __launch_bounds__(256) void xproj_gemm(
    const float* __restrict__ X, const float* __restrict__ W,
    const float* __restrict__ bih, const float* __restrict__ bhh,
    float* __restrict__ out)
{
  __shared__ short As[BM * KP];
  __shared__ short Bs[BN * KP];
  const int t  = threadIdx.x;
  const int mt = blockIdx.x >> 2;
  const int nt = blockIdx.x & 3;
  const int m0 = mt * BM, n0 = nt * BN;
  const int lane = t & 63, wv = t >> 6;
  const int wm = (wv & 1) * 64, wn = (wv >> 1) * 64;
  const int l15 = lane & 15, l4 = lane >> 4;

  const int sr = t >> 1;
  const int sk = (t & 1) * 16;
  const float* xa = X + (size_t)(m0 + sr) * NI + sk;
  const float* wa = W + (size_t)(n0 + sr) * NI + sk;
  short* asw = &As[sr * KP + sk];
  short* bsw = &Bs[sr * KP + sk];

  f32x4 acc[4][4];
  #pragma unroll
  for (int i = 0; i < 4; ++i)
    #pragma unroll
    for (int j = 0; j < 4; ++j)
      acc[i][j] = (f32x4){0.f, 0.f, 0.f, 0.f};

  for (int kt = 0; kt < NI; kt += BK) {
    float4 a0 = *(const float4*)(xa + kt);
    float4 a1 = *(const float4*)(xa + kt + 4);
    float4 a2 = *(const float4*)(xa + kt + 8);
    float4 a3 = *(const float4*)(xa + kt + 12);
    float4 b0 = *(const float4*)(wa + kt);
    float4 b1 = *(const float4*)(wa + kt + 4);
    float4 b2 = *(const float4*)(wa + kt + 8);
    float4 b3 = *(const float4*)(wa + kt + 12);
    s16x8 av0 = { f2bf(a0.x), f2bf(a0.y), f2bf(a0.z), f2bf(a0.w),
                  f2bf(a1.x), f2bf(a1.y), f2bf(a1.z), f2bf(a1.w) };
    s16x8 av1 = { f2bf(a2.x), f2bf(a2.y), f2bf(a2.z), f2bf(a2.w),
                  f2bf(a3.x), f2bf(a3.y), f2bf(a3.z), f2bf(a3.w) };
    s16x8 bv0 = { f2bf(b0.x), f2bf(b0.y), f2bf(b0.z), f2bf(b0.w),
                  f2bf(b1.x), f2bf(b1.y), f2bf(b1.z), f2bf(b1.w) };
    s16x8 bv1 = { f2bf(b2.x), f2bf(b2.y), f2bf(b2.z), f2bf(b2.w),
                  f2bf(b3.x), f2bf(b3.y), f2bf(b3.z), f2bf(b3.w) };

    __syncthreads();
    *(s16x8*)asw       = av0;
    *(s16x8*)(asw + 8) = av1;
    *(s16x8*)bsw       = bv0;
    *(s16x8*)(bsw + 8) = bv1;
    __syncthreads();

    s16x8 af[4], bf[4];
    #pragma unroll
    for (int mi = 0; mi < 4; ++mi)
      af[mi] = *(const s16x8*)&As[(wm + mi * 16 + l15) * KP + l4 * 8];
    #pragma unroll
    for (int ni = 0; ni < 4; ++ni)
      bf[ni] = *(const s16x8*)&Bs[(wn + ni * 16 + l15) * KP + l4 * 8];
    #pragma unroll
    for (int mi = 0; mi < 4; ++mi)
      #pragma unroll
      for (int ni = 0; ni < 4; ++ni)
        acc[mi][ni] = __builtin_amdgcn_mfma_f32_16x16x32_bf16(
            af[mi], bf[ni], acc[mi][ni], 0, 0, 0);
  }

  #pragma unroll
  for (int ni = 0; ni < 4; ++ni) {
    const int nloc = n0 + wn + ni * 16 + l15;
    const float bias = bih[nloc] + bhh[nloc];
    #pragma unroll
    for (int mi = 0; mi < 4; ++mi) {
      const int mrow = m0 + wm + mi * 16 + l4 * 4;
      #pragma unroll
      for (int j = 0; j < 4; ++j)
        out[(size_t)(mrow + j) * NH + nloc] = acc[mi][ni][j] + bias;
    }
  }
}

// ---------------- Kernel 2: per-batch recurrence, zero cross-WG sync ----------
// Thread t owns h-row t. Cols 0..383 of W_hh[t] in 192 NAMED+ASM-PINNED f16x2
// registers; cols 384..511 in LDS wq (16 f16x8 chunks = 128KB).
// h double-buffered in LDS as 256 f16x2, broadcast ds_read_b128.

#define KV 192                 // f16x2 pairs in VGPRs (cols < 384)
#define KQ 16                  // f16x8 chunks per row in LDS (cols [384,512))

#define FOR48(M) \
  M(0) M(1) M(2) M(3) M(4) M(5) M(6) M(7) M(8) M(9) \
  M(10) M(11) M(12) M(13) M(14) M(15) M(16) M(17) M(18) M(19) \
  M(20) M(21) M(22) M(23) M(24) M(25) M(26) M(27) M(28) M(29) \
  M(30) M(31) M(32) M(33) M(34) M(35) M(36) M(37) M(38) M(39) \
  M(40) M(41) M(42) M(43) M(44) M(45) M(46) M(47)

#define WDECL(g) f16x2 w##g##_0, w##g##_1, w##g##_2, w##g##_3;

#define WLOAD(g) { \
  float4 fa = row4[2 * (g)]; \
  float4 fb = row4[2 * (g) + 1]; \
  w##g##_0 = (f16x2){ (f16)fa.x, (f16)fa.y }; \
  w##g##_1 = (f16x2){ (f16)fa.z, (f16)fa.w }; \
  w##g##_2 = (f16x2){ (f16)fb.x, (f16)fb.y }; \
  w##g##_3 = (f16x2){ (f16)fb.z, (f16)fb.w }; }

// Pin: value becomes asm-defined -> not rematerializable, def can't sink into
// the loop, so RA must keep it resident (or spill to scratch, visible in TCC).
#define WPIN(g) asm volatile("" : "+v"(w##g##_0), "+v"(w##g##_1), \
                                  "+v"(w##g##_2), "+v"(w##g##_3));

#define WDOT(g) { \
  f16x8 hc = *(const f16x8*)&hb[4 * (g)]; \
  a0 = dot2(w##g##_0, (f16x2){ hc[0], hc[1] }, a0); \
  a1 = dot2(w##g##_1, (f16x2){ hc[2], hc[3] }, a1); \
  a2 = dot2(w##g##_2, (f16x2){ hc[4], hc[5] }, a2); \
  a3 = dot2(w##g##_3, (f16x2){ hc[6], hc[7] }, a3); }

__global__ __attribute__((amdgpu_flat_work_group_size(512, 512),
                          amdgpu_waves_per_eu(2, 2)))
void rnn_steps(const float* __restrict__ Whh, float* __restrict__ out)
{
  extern __shared__ f16x8 wq_raw[];                // [KQ][512]
  f16x8 (*wq)[512] = (f16x8(*)[512])wq_raw;
  __shared__ __align__(16) f16x2 hbuf[2][256];

  const int b = blockIdx.x;
  const int t = threadIdx.x;

  // ---- load W row t: cols 0..383 -> pinned VGPRs, 384..511 -> LDS ----
  const float4* row4 = (const float4*)(Whh + (size_t)t * NH);
  FOR48(WDECL)
  FOR48(WLOAD)
  FOR48(WPIN)
  #pragma unroll
  for (int q = 0; q < KQ; ++q) {                   // cols 384..511
    float4 fa = row4[KV / 2 + 2 * q];
    float4 fb = row4[KV / 2 + 2 * q + 1];
    wq[q][t] = (f16x8){ (f16)fa.x, (f16)fa.y, (f16)fa.z, (f16)fa.w,
                        (f16)fb.x, (f16)fb.y, (f16)fb.z, (f16)fb.w };
  }
  if (t < 256) {
    hbuf[0][t] = (f16x2){ (f16)0.f, (f16)0.f };
  }

  float* outp = out + (size_t)b * (NS * NH) + t;
  float xpv = outp[0];                       // xp for s=0 (xproj output)
  __syncthreads();

  for (int s = 0; s < NS; ++s) {
    // prefetch next step's xp early: latency hides under the dot product
    float xq = 0.f;
    if (s + 1 < NS) xq = outp[(size_t)(s + 1) * NH];

    const f16x2* hb = hbuf[s & 1];
    float a0 = 0.f, a1 = 0.f, a2 = 0.f, a3 = 0.f;
    FOR48(WDOT)                               // cols [0,384): W from VGPRs
    #pragma unroll
    for (int q = 0; q < KQ; ++q) {            // cols [384,512): W from LDS
      f16x8 wc = wq[q][t];                    // lane-consecutive 16B
      f16x8 hc = *(const f16x8*)&hb[KV + 4 * q];
      f16x2 w0 = { wc[0], wc[1] }, w1 = { wc[2], wc[3] };
      f16x2 w2 = { wc[4], wc[5] }, w3 = { wc[6], wc[7] };
      f16x2 h0 = { hc[0], hc[1] }, h1 = { hc[2], hc[3] };
      f16x2 h2 = { hc[4], hc[5] }, h3 = { hc[6], hc[7] };
      a0 = dot2(w0, h0, a0);
      a1 = dot2(w1, h1, a1);
      a2 = dot2(w2, h2, a2);
      a3 = dot2(w3, h3, a3);
    }
    const float y = (a0 + a1) + (a2 + a3);
    const float hval = tanh_fast(xpv + y);

    outp[(size_t)s * NH] = hval;              // coalesced 2KB store
    const float hnb = __shfl_xor(hval, 1);    // row-pair partner
    if ((t & 1) == 0)
      hbuf[(s + 1) & 1][t >> 1] = (f16x2){ (f16)hval, (f16)hnb };
    xpv = xq;
    __syncthreads();                          // next buffer ready
  }
}

// ---------------- launch ----------------
extern "C" void kernel_launch(void* const* d_in, const int* in_sizes, int n_in,
                              void* d_out, int out_size, void* d_ws, size_t ws_size,
                              hipStream_t stream) {
  const float* x   = (const float*)d_in[0];
  const float* Wih = (const float*)d_in[1];
  const float* Whh = (const float*)d_in[2];
  const float* bih = (const float*)d_in[3];
  const float* bhh = (const float*)d_in[4];
  float* out = (float*)d_out;

  xproj_gemm<<<dim3((NB * NS / BM) * (NH / BN)), dim3(256), 0, stream>>>(
      x, Wih, bih, bhh, out);

  const int dyn_lds = KQ * 512 * sizeof(f16x8);   // 128KB
  hipFuncSetAttribute((const void*)rnn_steps,
                      hipFuncAttributeMaxDynamicSharedMemorySize, dyn_lds);
  rnn_steps<<<dim3(NB), dim3(512), dyn_lds, stream>>>(Whh, out);
}